// Round 1
// 599.035 us; speedup vs baseline: 1.1806x; 1.1806x over previous
//
#include <hip/hip_runtime.h>

typedef unsigned short u16;
typedef unsigned int u32;
typedef __attribute__((ext_vector_type(8))) short short8;
typedef __attribute__((ext_vector_type(4))) float floatx4;

#define LN_EPS 1e-5f

__device__ __forceinline__ float bf2f(u16 u) {
    union { u32 i; float f; } v; v.i = ((u32)u) << 16; return v.f;
}
__device__ __forceinline__ u16 f2bf(float f) {
    union { u32 i; float f; } v; v.f = f;
    u32 x = v.i;
    return (u16)((x + 0x7fffu + ((x >> 16) & 1u)) >> 16);
}
__device__ __forceinline__ int clampi(int v, int lo, int hi) {
    return v < lo ? lo : (v > hi ? hi : v);
}

// Diagnostic fill (f32).
__global__ void k_fill(float* __restrict__ out, int nel, float val) {
    int i = blockIdx.x * blockDim.x + threadIdx.x;
    if (i < nel) out[i] = val;
}

// ---------------- preprocessing ----------------
__global__ void k_zero(int* p, int n) {
    int i = blockIdx.x * blockDim.x + threadIdx.x;
    if (i < n) p[i] = 0;
}

__global__ void k_detect(const int* __restrict__ ei, int E, int* __restrict__ flag) {
    __shared__ int any;
    if (threadIdx.x == 0) any = 0;
    __syncthreads();
    int lim = (E < 4096) ? E : 4096;
    int v = 0;
    for (int i = threadIdx.x; i < lim; i += 256) v |= ei[2 * i + 1];
    if (v) atomicOr(&any, 1);
    __syncthreads();
    if (threadIdx.x == 0) flag[0] = (any == 0) ? 1 : 0;
}

__global__ void k_hist(const int* __restrict__ ei, const int* __restrict__ flag,
                       int* __restrict__ deg, int E, int n) {
    int e = blockIdx.x * blockDim.x + threadIdx.x;
    if (e < E) {
        int d = flag[0] ? ei[2 * ((size_t)E + e)] : ei[(size_t)E + e];
        atomicAdd(&deg[clampi(d, 0, n - 1)], 1);
    }
}

__global__ void k_scan1(const int* __restrict__ deg, int* __restrict__ offs,
                        int* __restrict__ bsum, int n) {
    __shared__ int s[256];
    int t = threadIdx.x;
    int i = blockIdx.x * 256 + t;
    int v = (i < n) ? deg[i] : 0;
    s[t] = v; __syncthreads();
    for (int off = 1; off < 256; off <<= 1) {
        int x = (t >= off) ? s[t - off] : 0;
        __syncthreads();
        s[t] += x;
        __syncthreads();
    }
    if (i < n) offs[i] = s[t] - v;
    if (t == 255) bsum[blockIdx.x] = s[255];
}

__global__ void k_scan2(int* bsum, int nb) {
    __shared__ int s[256];
    int t = threadIdx.x;
    int v = (t < nb) ? bsum[t] : 0;
    s[t] = v; __syncthreads();
    for (int off = 1; off < 256; off <<= 1) {
        int x = (t >= off) ? s[t - off] : 0;
        __syncthreads();
        s[t] += x;
        __syncthreads();
    }
    if (t < nb) bsum[t] = s[t] - v;
}

__global__ void k_scan3(int* __restrict__ offs, const int* __restrict__ bsum,
                        int* __restrict__ cursor, int n, int E) {
    int i = blockIdx.x * 256 + threadIdx.x;
    if (i < n) {
        int v = offs[i] + bsum[blockIdx.x];
        offs[i] = v;
        cursor[i] = v;
    }
    if (i == 0) offs[n] = E;
}

__global__ void k_scatter(const int* __restrict__ ei, const int* __restrict__ flag,
                          int* __restrict__ cursor,
                          int* __restrict__ perm, int* __restrict__ srcs,
                          int* __restrict__ dsts, int E, int n) {
    int e = blockIdx.x * blockDim.x + threadIdx.x;
    if (e < E) {
        int sv, dv;
        if (flag[0]) {
            sv = ei[2 * (size_t)e];
            dv = ei[2 * ((size_t)E + e)];
        } else {
            sv = ei[e];
            dv = ei[(size_t)E + e];
        }
        sv = clampi(sv, 0, n - 1);
        dv = clampi(dv, 0, n - 1);
        int p = clampi(atomicAdd(&cursor[dv], 1), 0, E - 1);
        perm[p] = e;
        srcs[p] = sv;
        dsts[p] = dv;
    }
}

// Pre-swizzle f32 weights into bf16 MFMA B-fragment order:
// B[k][n], k = kt*32 + q*8 + j  ->  idx = ((kt*4+q)*N + n)*8 + j
__global__ void k_swz(const float* __restrict__ W1, const float* __restrict__ W2,
                      const float* __restrict__ Wr, const float* __restrict__ nW,
                      u16* __restrict__ W1s, u16* __restrict__ W2s,
                      u16* __restrict__ Wrs, u16* __restrict__ nWs) {
    int i = blockIdx.x * blockDim.x + threadIdx.x;
    if (i < 3 * 24576) {
        int l = i / 24576, rem = i % 24576;
        int k = rem / 128, n = rem % 128;
        int kt = k >> 5, q = (k >> 3) & 3, j = k & 7;
        W1s[l * 24576 + ((kt * 4 + q) * 128 + n) * 8 + j] = f2bf(W1[i]);
    }
    if (i < 3 * 8192) {
        int l = i / 8192, rem = i % 8192;
        int k = rem / 64, n = rem % 64;
        int kt = k >> 5, q = (k >> 3) & 3, j = k & 7;
        W2s[l * 8192 + ((kt * 4 + q) * 64 + n) * 8 + j] = f2bf(W2[i]);
    }
    if (i < 3 * 4096) {
        int l = i / 4096, rem = i % 4096;
        int k = rem / 64, n = rem % 64;
        int kt = k >> 5, q = (k >> 3) & 3, j = k & 7;
        Wrs[l * 4096 + ((kt * 4 + q) * 64 + n) * 8 + j] = f2bf(Wr[i]);
    }
    if (i < 8192) {
        int k = i / 64, n = i % 64;
        int kt = k >> 5, q = (k >> 3) & 3, j = k & 7;
        nWs[((kt * 4 + q) * 64 + n) * 8 + j] = f2bf(nW[i]);
    }
}

// ---------------- node encoder (MFMA, LDS-free, barrier-free) ----------------
// 512 threads = 8 waves; wave handles 16 rows. A-frags converted f32->bf16 in regs.
__global__ __launch_bounds__(512) void k_node_enc(
    const float* __restrict__ x, const u16* __restrict__ nWs, const float* __restrict__ bias,
    float* __restrict__ h, u16* __restrict__ hn, int n) {
    int t = threadIdx.x;
    int w = t >> 6, l = t & 63, q = l >> 4, ml = l & 15;
    int wbase = blockIdx.x * 128 + w * 16;
    int rin = wbase + ml;
    int rr = (rin < n) ? rin : 0;
    const float* xr = x + (size_t)rr * 128;
    short8 a[4];
#pragma unroll
    for (int kt = 0; kt < 4; kt++) {
        float4 f0 = *((const float4*)(xr + kt * 32 + q * 8));
        float4 f1 = *((const float4*)(xr + kt * 32 + q * 8 + 4));
        a[kt][0] = (short)f2bf(f0.x); a[kt][1] = (short)f2bf(f0.y);
        a[kt][2] = (short)f2bf(f0.z); a[kt][3] = (short)f2bf(f0.w);
        a[kt][4] = (short)f2bf(f1.x); a[kt][5] = (short)f2bf(f1.y);
        a[kt][6] = (short)f2bf(f1.z); a[kt][7] = (short)f2bf(f1.w);
    }
    float bc[4];
#pragma unroll
    for (int nt = 0; nt < 4; nt++) bc[nt] = bias[nt * 16 + ml];
    floatx4 acc[4];
#pragma unroll
    for (int nt = 0; nt < 4; nt++) acc[nt] = floatx4{0.f, 0.f, 0.f, 0.f};
#pragma unroll
    for (int kt = 0; kt < 4; kt++) {
#pragma unroll
        for (int nt = 0; nt < 4; nt++) {
            short8 bf = *((const short8*)(nWs + (size_t)((kt * 4 + q) * 64 + nt * 16 + ml) * 8));
            acc[nt] = __builtin_amdgcn_mfma_f32_16x16x32_bf16(a[kt], bf, acc[nt], 0, 0, 0);
        }
    }
#pragma unroll
    for (int nt = 0; nt < 4; nt++) {
#pragma unroll
        for (int r2 = 0; r2 < 4; r2++) {
            int pos = wbase + q * 4 + r2;
            if (pos < n) {
                float v = acc[nt][r2] + bc[nt];
                size_t idx = (size_t)pos * 64 + nt * 16 + ml;
                h[idx] = v;
                hn[idx] = f2bf(v);
            }
        }
    }
}

// Thread-per-(edge, 16-ch quarter): fully independent threads, no shuffles.
__global__ __launch_bounds__(256) void k_edge_enc(
    const float* __restrict__ ea, const int* __restrict__ perm,
    const float* __restrict__ W, const float* __restrict__ bias,
    u16* __restrict__ e_s, int E) {
    __shared__ float4 sW4[16 * 16];   // W[16][64] as float4 [k][c/4], 4 KB
    int t = threadIdx.x;
    if (t < 256) sW4[t] = ((const float4*)W)[t];
    __syncthreads();
    int gid = blockIdx.x * 256 + t;
    int eidx = gid >> 2, qq = gid & 3;
    if (eidx >= E) return;
    int e = perm[eidx];
    const float4* row4 = (const float4*)(ea + (size_t)e * 16);
    float4 r4[4];
    r4[0] = row4[0]; r4[1] = row4[1]; r4[2] = row4[2]; r4[3] = row4[3];
    const float* row = (const float*)r4;
    float4 acc[4];
#pragma unroll
    for (int j = 0; j < 4; j++) acc[j] = ((const float4*)bias)[qq * 4 + j];
#pragma unroll
    for (int k = 0; k < 16; k++) {
        float rv = row[k];
#pragma unroll
        for (int j = 0; j < 4; j++) {
            float4 wv = sW4[k * 16 + qq * 4 + j];
            acc[j].x += rv * wv.x; acc[j].y += rv * wv.y;
            acc[j].z += rv * wv.z; acc[j].w += rv * wv.w;
        }
    }
    u32 pk[8];
#pragma unroll
    for (int j = 0; j < 4; j++) {
        pk[2 * j]     = (u32)f2bf(acc[j].x) | ((u32)f2bf(acc[j].y) << 16);
        pk[2 * j + 1] = (u32)f2bf(acc[j].z) | ((u32)f2bf(acc[j].w) << 16);
    }
    uint4* outp = (uint4*)(e_s + (size_t)eidx * 64 + qq * 16);
    outp[0] = make_uint4(pk[0], pk[1], pk[2], pk[3]);
    outp[1] = make_uint4(pk[4], pk[5], pk[6], pk[7]);
}

// ---------------- layernorm: bf16-out (hn producer) and f32-out (final) ----------------
__global__ __launch_bounds__(256) void k_lnorm_bf(
    const float* __restrict__ h, const float* __restrict__ g, const float* __restrict__ b,
    u16* __restrict__ out, int n) {
    int t = threadIdx.x, wid = t >> 6, lane = t & 63;
    float gc = g[lane], bc = b[lane];
    for (int row = blockIdx.x * 4 + wid; row < n; row += gridDim.x * 4) {
        float v = h[(size_t)row * 64 + lane];
        float s = v;
#pragma unroll
        for (int o = 32; o > 0; o >>= 1) s += __shfl_xor(s, o);
        float mu = s * (1.f / 64.f);
        float d = v - mu;
        float s2 = d * d;
#pragma unroll
        for (int o = 32; o > 0; o >>= 1) s2 += __shfl_xor(s2, o);
        float inv = rsqrtf(s2 * (1.f / 64.f) + LN_EPS);
        float r = fmaxf(d * inv * gc + bc, 0.f);
        out[(size_t)row * 64 + lane] = f2bf(r);
    }
}

__global__ __launch_bounds__(256) void k_lnorm_out(
    const float* __restrict__ h, const float* __restrict__ g, const float* __restrict__ b,
    float* __restrict__ out, int n) {
    int t = threadIdx.x, wid = t >> 6, lane = t & 63;
    float gc = g[lane], bc = b[lane];
    for (int row = blockIdx.x * 4 + wid; row < n; row += gridDim.x * 4) {
        float v = h[(size_t)row * 64 + lane];
        float s = v;
#pragma unroll
        for (int o = 32; o > 0; o >>= 1) s += __shfl_xor(s, o);
        float mu = s * (1.f / 64.f);
        float d = v - mu;
        float s2 = d * d;
#pragma unroll
        for (int o = 32; o > 0; o >>= 1) s2 += __shfl_xor(s2, o);
        float inv = rsqrtf(s2 * (1.f / 64.f) + LN_EPS);
        out[(size_t)row * 64 + lane] = fmaxf(d * inv * gc + bc, 0.f);
    }
}

// ---------------- edge MLP (MFMA, LDS-staged weights — R1) ----------------
// Weights staged to LDS once per block: W1s (48 KB) into sShared, W2s (16 KB)
// into sW2L. After the W1 MFMA phase (barrier), the per-wave arenas overlay the
// dead W1 region, keeping total LDS at 64 KB -> 2 blocks/CU.
// B-frag ds_read_b128 pattern is 8 dwords/bank uniform = conflict-free minimum.
#define TILE 128
#define HSTR 136
__global__ __launch_bounds__(512, 4) void k_mlp(
    const u16* __restrict__ hn, const u16* __restrict__ e_s,
    const int* __restrict__ dsts, const int* __restrict__ srcs,
    const u16* __restrict__ W1s, const float* __restrict__ b1,
    const u16* __restrict__ W2s, const float* __restrict__ b2,
    const float* __restrict__ elng, const float* __restrict__ elnb,
    int ln_edge, u16* __restrict__ m_out, int E) {
    __shared__ __align__(16) short sW2L[8192];      // 16 KB: W2 frags (live whole kernel)
    __shared__ __align__(16) short sShared[24576];  // 48 KB: W1 frags, then per-wave arenas

    int t = threadIdx.x;
    int w = t >> 6, l = t & 63, q = l >> 4, ml = l & 15;
    int base = blockIdx.x * TILE + w * 16;
    int pos = base + ml;
    bool act = pos < E;
    int pp = act ? pos : 0;
    int dn = act ? dsts[pos] : 0;
    int sn = act ? srcs[pos] : 0;

    // Issue per-edge gathers first (independent of staging; overlaps latency).
    short8 a[6];
    a[0] = *(const short8*)(hn + (size_t)dn * 64 + q * 8);
    a[1] = *(const short8*)(hn + (size_t)dn * 64 + 32 + q * 8);
    a[2] = *(const short8*)(hn + (size_t)sn * 64 + q * 8);
    a[3] = *(const short8*)(hn + (size_t)sn * 64 + 32 + q * 8);
    short8 e0 = *(const short8*)(e_s + (size_t)pp * 64 + q * 8);
    short8 e1 = *(const short8*)(e_s + (size_t)pp * 64 + 32 + q * 8);

    // Stage weights global -> LDS (linear copy; frag order already pre-swizzled).
    {
        const uint4* g1 = (const uint4*)W1s;
        uint4* s1 = (uint4*)sShared;
#pragma unroll
        for (int j = 0; j < 6; j++) s1[t + j * 512] = g1[t + j * 512];
        const uint4* g2 = (const uint4*)W2s;
        uint4* s2 = (uint4*)sW2L;
#pragma unroll
        for (int j = 0; j < 2; j++) s2[t + j * 512] = g2[t + j * 512];
    }

    if (ln_edge) {
        float ev[16];
        float sm = 0.f, sq = 0.f;
#pragma unroll
        for (int i = 0; i < 8; i++) {
            float f0 = bf2f((u16)e0[i]);
            float f1 = bf2f((u16)e1[i]);
            ev[i] = f0; ev[8 + i] = f1;
            sm += f0 + f1; sq += f0 * f0 + f1 * f1;
        }
        sm += __shfl_xor(sm, 16); sm += __shfl_xor(sm, 32);
        sq += __shfl_xor(sq, 16); sq += __shfl_xor(sq, 32);
        float mu = sm * (1.f / 64.f);
        float var = sq * (1.f / 64.f) - mu * mu;
        float inv = rsqrtf(fmaxf(var, 0.f) + LN_EPS);
#pragma unroll
        for (int i = 0; i < 8; i++) {
            int c0 = q * 8 + i, c1 = 32 + q * 8 + i;
            a[4][i] = (short)f2bf((ev[i] - mu) * inv * elng[c0] + elnb[c0]);
            a[5][i] = (short)f2bf((ev[8 + i] - mu) * inv * elng[c1] + elnb[c1]);
        }
    } else {
        a[4] = e0; a[5] = e1;
    }

    float b1c[8], b2c[4];
#pragma unroll
    for (int nt = 0; nt < 8; nt++) b1c[nt] = b1[nt * 16 + ml];
#pragma unroll
    for (int nt = 0; nt < 4; nt++) b2c[nt] = b2[nt * 16 + ml];

    __syncthreads();   // weights staged

    floatx4 acc[8];
#pragma unroll
    for (int nt = 0; nt < 8; nt++) acc[nt] = floatx4{0.f, 0.f, 0.f, 0.f};
#pragma unroll
    for (int kt = 0; kt < 6; kt++) {
#pragma unroll
        for (int nt = 0; nt < 8; nt++) {
            short8 bf = *((const short8*)(sShared + ((kt * 4 + q) * 128 + nt * 16 + ml) * 8));
            acc[nt] = __builtin_amdgcn_mfma_f32_16x16x32_bf16(a[kt], bf, acc[nt], 0, 0, 0);
        }
    }

    __syncthreads();   // all waves done reading W1 frags; arenas may overlay

    short* arena = sShared + w * 16 * HSTR;
#pragma unroll
    for (int nt = 0; nt < 8; nt++) {
#pragma unroll
        for (int r2 = 0; r2 < 4; r2++) {
            float v = fmaxf(acc[nt][r2] + b1c[nt], 0.f);
            ((u16*)arena)[(q * 4 + r2) * HSTR + nt * 16 + ml] = f2bf(v);
        }
    }

    floatx4 acc2[4];
#pragma unroll
    for (int nt = 0; nt < 4; nt++) acc2[nt] = floatx4{0.f, 0.f, 0.f, 0.f};
#pragma unroll
    for (int kt = 0; kt < 4; kt++) {
        short8 ah = *((const short8*)(arena + ml * HSTR + kt * 32 + q * 8));
#pragma unroll
        for (int nt = 0; nt < 4; nt++) {
            short8 bf = *((const short8*)(sW2L + ((kt * 4 + q) * 64 + nt * 16 + ml) * 8));
            acc2[nt] = __builtin_amdgcn_mfma_f32_16x16x32_bf16(ah, bf, acc2[nt], 0, 0, 0);
        }
    }

#pragma unroll
    for (int nt = 0; nt < 4; nt++) {
#pragma unroll
        for (int r2 = 0; r2 < 4; r2++) {
            ((u16*)arena)[(q * 4 + r2) * HSTR + nt * 16 + ml] = f2bf(acc2[nt][r2] + b2c[nt]);
        }
    }
    short8 m0 = *((const short8*)(arena + ml * HSTR + q * 16));
    short8 m1 = *((const short8*)(arena + ml * HSTR + q * 16 + 8));
    if (act) {
        *((short8*)(m_out + (size_t)pos * 64 + q * 16)) = m0;
        *((short8*)(m_out + (size_t)pos * 64 + q * 16 + 8)) = m1;
    }
}

// ---------------- root weight: h = (add_h?h:0) + hn @ Wr  (MFMA) ----------------
__global__ __launch_bounds__(512) void k_root(
    const u16* __restrict__ hn, const u16* __restrict__ Wrs,
    float* __restrict__ h, int add_h, int n) {
    __shared__ short sA[8 * 1024];   // 16 KB
    int t = threadIdx.x;
    int base = blockIdx.x * 128;
    {
        int r = t >> 2, s = t & 3;
        int pos = base + r;
        int g = r >> 4, m = r & 15;
        short* grp = sA + g * 1024;
        bool act = pos < n;
        uint4 z4 = make_uint4(0, 0, 0, 0);
        const uint4* pd = (const uint4*)(hn + (size_t)(act ? pos : 0) * 64);
        uint4 d0 = act ? pd[2 * s] : z4;
        uint4 d1 = act ? pd[2 * s + 1] : z4;
        int ch = (s >> 1) * 4 + (s & 1) * 2;
        *((uint4*)(grp + ch * 128 + m * 8)) = d0;
        *((uint4*)(grp + (ch + 1) * 128 + m * 8)) = d1;
    }
    __syncthreads();
    int w = t >> 6, l = t & 63, q = l >> 4, ml = l & 15;
    short* arena = sA + w * 1024;
    floatx4 acc[4];
#pragma unroll
    for (int nt = 0; nt < 4; nt++) acc[nt] = floatx4{0.f, 0.f, 0.f, 0.f};
#pragma unroll
    for (int kt = 0; kt < 2; kt++) {
        short8 a = *((const short8*)(arena + (kt * 4 + q) * 128 + ml * 8));
#pragma unroll
        for (int nt = 0; nt < 4; nt++) {
            short8 bf = *((const short8*)(Wrs + (size_t)((kt * 4 + q) * 64 + nt * 16 + ml) * 8));
            acc[nt] = __builtin_amdgcn_mfma_f32_16x16x32_bf16(a, bf, acc[nt], 0, 0, 0);
        }
    }
#pragma unroll
    for (int nt = 0; nt < 4; nt++) {
#pragma unroll
        for (int r2 = 0; r2 < 4; r2++) {
            int pos = base + w * 16 + q * 4 + r2;
            if (pos < n) {
                size_t idx = (size_t)pos * 64 + nt * 16 + ml;
                float v = acc[nt][r2];
                h[idx] = add_h ? (h[idx] + v) : v;
            }
        }
    }
}

// ---------------- e += m (vectorized elementwise, bf16) ----------------
__global__ void k_eadd(u16* __restrict__ dst, const u16* __restrict__ src, long nv) {
    long i = (long)blockIdx.x * blockDim.x + threadIdx.x;
    if (i < nv) {
        uint4 a = ((const uint4*)dst)[i];
        uint4 b = ((const uint4*)src)[i];
        u32* pa = (u32*)&a;
        const u32* pb = (const u32*)&b;
        uint4 r;
        u32* pr = (u32*)&r;
#pragma unroll
        for (int k = 0; k < 4; k++) {
            float lo = bf2f((u16)(pa[k] & 0xffffu)) + bf2f((u16)(pb[k] & 0xffffu));
            float hi = bf2f((u16)(pa[k] >> 16)) + bf2f((u16)(pb[k] >> 16));
            pr[k] = (u32)f2bf(lo) | ((u32)f2bf(hi) << 16);
        }
        ((uint4*)dst)[i] = r;
    }
}

// ---------------- aggregation: online softmax over CSR, 2x unrolled ----------------
__global__ __launch_bounds__(256) void k_agg2(
    const u16* __restrict__ m_s, float* __restrict__ h,
    const int* __restrict__ offs, const float* __restrict__ tptr, int tidx,
    int n, int E) {
    int t = threadIdx.x, wid = t >> 6, lane = t & 63;
    float tv = tptr[tidx];
    for (int node = blockIdx.x * 4 + wid; node < n; node += gridDim.x * 4) {
        int p0 = clampi(offs[node], 0, E);
        int p1 = clampi(offs[node + 1], p0, E);
        float M = -1e30f, D = 0.f, S = 0.f;
        int p = p0;
        for (; p + 1 < p1; p += 2) {
            float mv0 = bf2f(m_s[(size_t)p * 64 + lane]);
            float mv1 = bf2f(m_s[(size_t)(p + 1) * 64 + lane]);
            float lg0 = mv0 * tv, lg1 = mv1 * tv;
            float Mp = fmaxf(lg0, lg1);
            float a0 = __expf(lg0 - Mp), a1 = __expf(lg1 - Mp);
            float Dp = a0 + a1, Sp = mv0 * a0 + mv1 * a1;
            float Mn = fmaxf(M, Mp);
            float xx = __expf(M - Mn), yy = __expf(Mp - Mn);
            D = D * xx + Dp * yy;
            S = S * xx + Sp * yy;
            M = Mn;
        }
        if (p < p1) {
            float mv = bf2f(m_s[(size_t)p * 64 + lane]);
            float lg = mv * tv;
            float Mn = fmaxf(M, lg);
            float xx = __expf(M - Mn), yy = __expf(lg - Mn);
            D = D * xx + yy;
            S = S * xx + mv * yy;
        }
        if (p1 > p0) h[(size_t)node * 64 + lane] += S / D;
    }
}

// ---------------- launcher ----------------
extern "C" void kernel_launch(void* const* d_in, const int* in_sizes, int n_in,
                              void* d_out, int out_size, void* d_ws, size_t ws_size,
                              hipStream_t stream) {
    float* outp = (float*)d_out;
    int FB = (out_size + 255) / 256;

    if (n_in != 17) {
        k_fill<<<FB, 256, 0, stream>>>(outp, out_size, 3.0f);
        return;
    }

    const float* x    = (const float*)d_in[0];
    const int*   ei   = (const int*)d_in[1];
    const float* ea   = (const float*)d_in[2];
    const float* nW   = (const float*)d_in[3];
    const float* nb   = (const float*)d_in[4];
    const float* eW   = (const float*)d_in[5];
    const float* eb   = (const float*)d_in[6];
    const float* cW1  = (const float*)d_in[7];
    const float* cb1  = (const float*)d_in[8];
    const float* cW2  = (const float*)d_in[9];
    const float* cb2  = (const float*)d_in[10];
    const float* cWr  = (const float*)d_in[11];
    const float* ct   = (const float*)d_in[12];
    const float* lng  = (const float*)d_in[13];
    const float* lnb  = (const float*)d_in[14];
    const float* elng = (const float*)d_in[15];
    const float* elnb = (const float*)d_in[16];

    const int n = in_sizes[0] / 128;   // 50000
    const int E = in_sizes[2] / 16;    // 500000

    char* ws = (char*)d_ws;
    size_t o = 0;
    auto alloc = [&](size_t bytes) -> void* {
        void* p = ws + o;
        o += (bytes + 255) & ~(size_t)255;
        return p;
    };
    int*   flag   = (int*)alloc(256);
    int*   deg    = (int*)alloc((size_t)n * 4);
    int*   offs   = (int*)alloc((size_t)(n + 1) * 4);
    int*   cursor = (int*)alloc((size_t)n * 4);
    int*   bsum   = (int*)alloc(256 * 4);
    int*   perm   = (int*)alloc((size_t)E * 4);
    int*   srcs   = (int*)alloc((size_t)E * 4);
    int*   dsts   = (int*)alloc((size_t)E * 4);
    float* h      = (float*)alloc((size_t)n * 64 * 4);
    u16*   hn     = (u16*)alloc((size_t)n * 64 * 2);
    u16*   bufA   = (u16*)alloc((size_t)E * 64 * 2);
    u16*   bufB   = (u16*)alloc((size_t)E * 64 * 2);
    u16*   W1s    = (u16*)alloc((size_t)3 * 24576 * 2);
    u16*   W2s    = (u16*)alloc((size_t)3 * 8192 * 2);
    u16*   Wrs    = (u16*)alloc((size_t)3 * 4096 * 2);
    u16*   nWs    = (u16*)alloc((size_t)8192 * 2);

    k_fill<<<FB, 256, 0, stream>>>(outp, out_size, 1.0f);
    if (o > ws_size) {
        k_fill<<<FB, 256, 0, stream>>>(outp, out_size, 2.0f);
        return;
    }

    int SB = (n + 255) / 256;
    k_detect<<<1, 256, 0, stream>>>(ei, E, flag);
    k_zero<<<SB, 256, 0, stream>>>(deg, n);
    k_hist<<<(E + 255) / 256, 256, 0, stream>>>(ei, flag, deg, E, n);
    k_scan1<<<SB, 256, 0, stream>>>(deg, offs, bsum, n);
    k_scan2<<<1, 256, 0, stream>>>(bsum, SB);
    k_scan3<<<SB, 256, 0, stream>>>(offs, bsum, cursor, n, E);
    k_scatter<<<(E + 255) / 256, 256, 0, stream>>>(ei, flag, cursor, perm, srcs, dsts, E, n);
    k_swz<<<(3 * 24576 + 255) / 256, 256, 0, stream>>>(cW1, cW2, cWr, nW, W1s, W2s, Wrs, nWs);
    k_node_enc<<<(n + 127) / 128, 512, 0, stream>>>(x, nWs, nb, h, hn, n);
    k_edge_enc<<<(E * 4 + 255) / 256, 256, 0, stream>>>(ea, perm, eW, eb, bufA, E);

    // Buffer schedule (ping-pong, no copies) — R8 proven:
    //  L0: mlp(in=bufA) -> bufB(m1); agg reads bufB
    //  L1: mlp(in=bufB) -> bufA(m2); agg reads bufA; eadd: bufB += bufA
    //  L2: mlp(in=bufB) -> bufA(m3); agg reads bufA
    int MB = (E + TILE - 1) / TILE;
    int RB = (n + 127) / 128;
    int AB = (n + 3) / 4;
    long nv = (long)E * 64 / 8;
    int VB = (int)((nv + 255) / 256);

    const u16* mlp_in[3]  = { bufA, bufB, bufB };
    u16*       mlp_out[3] = { bufB, bufA, bufA };

    for (int i = 0; i < 3; i++) {
        if (i > 0)
            k_lnorm_bf<<<512, 256, 0, stream>>>(h, lng + (size_t)i * 64, lnb + (size_t)i * 64, hn, n);
        k_mlp<<<MB, 512, 0, stream>>>(
            hn, mlp_in[i], dsts, srcs,
            W1s + (size_t)i * 24576, cb1 + (size_t)i * 128,
            W2s + (size_t)i * 8192, cb2 + (size_t)i * 64,
            elng + (size_t)((i > 0) ? (i - 1) : 0) * 64,
            elnb + (size_t)((i > 0) ? (i - 1) : 0) * 64,
            (i > 0) ? 1 : 0, mlp_out[i], E);
        k_root<<<RB, 512, 0, stream>>>(hn, Wrs + (size_t)i * 4096, h, (i > 0) ? 1 : 0, n);
        k_agg2<<<AB, 256, 0, stream>>>(mlp_out[i], h, offs, ct, i, n, E);
        if (i == 1)
            k_eadd<<<VB, 256, 0, stream>>>(bufB, bufA, nv);
    }
    k_lnorm_out<<<512, 256, 0, stream>>>(h, lng, lnb, outp, n);
}

// Round 2
// 597.998 us; speedup vs baseline: 1.1827x; 1.0017x over previous
//
#include <hip/hip_runtime.h>

typedef unsigned short u16;
typedef unsigned int u32;
typedef __attribute__((ext_vector_type(8))) short short8;
typedef __attribute__((ext_vector_type(4))) float floatx4;

#define LN_EPS 1e-5f

__device__ __forceinline__ float bf2f(u16 u) {
    union { u32 i; float f; } v; v.i = ((u32)u) << 16; return v.f;
}
__device__ __forceinline__ u16 f2bf(float f) {
    union { u32 i; float f; } v; v.f = f;
    u32 x = v.i;
    return (u16)((x + 0x7fffu + ((x >> 16) & 1u)) >> 16);
}
__device__ __forceinline__ int clampi(int v, int lo, int hi) {
    return v < lo ? lo : (v > hi ? hi : v);
}

// Diagnostic fill (f32).
__global__ void k_fill(float* __restrict__ out, int nel, float val) {
    int i = blockIdx.x * blockDim.x + threadIdx.x;
    if (i < nel) out[i] = val;
}

// ---------------- preprocessing ----------------
__global__ void k_zero(int* p, int n) {
    int i = blockIdx.x * blockDim.x + threadIdx.x;
    if (i < n) p[i] = 0;
}

__global__ void k_detect(const int* __restrict__ ei, int E, int* __restrict__ flag) {
    __shared__ int any;
    if (threadIdx.x == 0) any = 0;
    __syncthreads();
    int lim = (E < 4096) ? E : 4096;
    int v = 0;
    for (int i = threadIdx.x; i < lim; i += 256) v |= ei[2 * i + 1];
    if (v) atomicOr(&any, 1);
    __syncthreads();
    if (threadIdx.x == 0) flag[0] = (any == 0) ? 1 : 0;
}

__global__ void k_hist(const int* __restrict__ ei, const int* __restrict__ flag,
                       int* __restrict__ deg, int E, int n) {
    int e = blockIdx.x * blockDim.x + threadIdx.x;
    if (e < E) {
        int d = flag[0] ? ei[2 * ((size_t)E + e)] : ei[(size_t)E + e];
        atomicAdd(&deg[clampi(d, 0, n - 1)], 1);
    }
}

__global__ void k_scan1(const int* __restrict__ deg, int* __restrict__ offs,
                        int* __restrict__ bsum, int n) {
    __shared__ int s[256];
    int t = threadIdx.x;
    int i = blockIdx.x * 256 + t;
    int v = (i < n) ? deg[i] : 0;
    s[t] = v; __syncthreads();
    for (int off = 1; off < 256; off <<= 1) {
        int x = (t >= off) ? s[t - off] : 0;
        __syncthreads();
        s[t] += x;
        __syncthreads();
    }
    if (i < n) offs[i] = s[t] - v;
    if (t == 255) bsum[blockIdx.x] = s[255];
}

__global__ void k_scan2(int* bsum, int nb) {
    __shared__ int s[256];
    int t = threadIdx.x;
    int v = (t < nb) ? bsum[t] : 0;
    s[t] = v; __syncthreads();
    for (int off = 1; off < 256; off <<= 1) {
        int x = (t >= off) ? s[t - off] : 0;
        __syncthreads();
        s[t] += x;
        __syncthreads();
    }
    if (t < nb) bsum[t] = s[t] - v;
}

__global__ void k_scan3(int* __restrict__ offs, const int* __restrict__ bsum,
                        int* __restrict__ cursor, int n, int E) {
    int i = blockIdx.x * 256 + threadIdx.x;
    if (i < n) {
        int v = offs[i] + bsum[blockIdx.x];
        offs[i] = v;
        cursor[i] = v;
    }
    if (i == 0) offs[n] = E;
}

__global__ void k_scatter(const int* __restrict__ ei, const int* __restrict__ flag,
                          int* __restrict__ cursor,
                          int* __restrict__ perm, int* __restrict__ srcs,
                          int* __restrict__ dsts, int E, int n) {
    int e = blockIdx.x * blockDim.x + threadIdx.x;
    if (e < E) {
        int sv, dv;
        if (flag[0]) {
            sv = ei[2 * (size_t)e];
            dv = ei[2 * ((size_t)E + e)];
        } else {
            sv = ei[e];
            dv = ei[(size_t)E + e];
        }
        sv = clampi(sv, 0, n - 1);
        dv = clampi(dv, 0, n - 1);
        int p = clampi(atomicAdd(&cursor[dv], 1), 0, E - 1);
        perm[p] = e;
        srcs[p] = sv;
        dsts[p] = dv;
    }
}

// Pre-swizzle f32 weights into bf16 MFMA B-fragment order:
// B[k][n], k = kt*32 + q*8 + j  ->  idx = ((kt*4+q)*N + n)*8 + j
__global__ void k_swz(const float* __restrict__ W1, const float* __restrict__ W2,
                      const float* __restrict__ Wr, const float* __restrict__ nW,
                      u16* __restrict__ W1s, u16* __restrict__ W2s,
                      u16* __restrict__ Wrs, u16* __restrict__ nWs) {
    int i = blockIdx.x * blockDim.x + threadIdx.x;
    if (i < 3 * 24576) {
        int l = i / 24576, rem = i % 24576;
        int k = rem / 128, n = rem % 128;
        int kt = k >> 5, q = (k >> 3) & 3, j = k & 7;
        W1s[l * 24576 + ((kt * 4 + q) * 128 + n) * 8 + j] = f2bf(W1[i]);
    }
    if (i < 3 * 8192) {
        int l = i / 8192, rem = i % 8192;
        int k = rem / 64, n = rem % 64;
        int kt = k >> 5, q = (k >> 3) & 3, j = k & 7;
        W2s[l * 8192 + ((kt * 4 + q) * 64 + n) * 8 + j] = f2bf(W2[i]);
    }
    if (i < 3 * 4096) {
        int l = i / 4096, rem = i % 4096;
        int k = rem / 64, n = rem % 64;
        int kt = k >> 5, q = (k >> 3) & 3, j = k & 7;
        Wrs[l * 4096 + ((kt * 4 + q) * 64 + n) * 8 + j] = f2bf(Wr[i]);
    }
    if (i < 8192) {
        int k = i / 64, n = i % 64;
        int kt = k >> 5, q = (k >> 3) & 3, j = k & 7;
        nWs[((kt * 4 + q) * 64 + n) * 8 + j] = f2bf(nW[i]);
    }
}

// ---------------- node encoder (MFMA, LDS-free, barrier-free) ----------------
// 512 threads = 8 waves; wave handles 16 rows. A-frags converted f32->bf16 in regs.
__global__ __launch_bounds__(512) void k_node_enc(
    const float* __restrict__ x, const u16* __restrict__ nWs, const float* __restrict__ bias,
    float* __restrict__ h, u16* __restrict__ hn, int n) {
    int t = threadIdx.x;
    int w = t >> 6, l = t & 63, q = l >> 4, ml = l & 15;
    int wbase = blockIdx.x * 128 + w * 16;
    int rin = wbase + ml;
    int rr = (rin < n) ? rin : 0;
    const float* xr = x + (size_t)rr * 128;
    short8 a[4];
#pragma unroll
    for (int kt = 0; kt < 4; kt++) {
        float4 f0 = *((const float4*)(xr + kt * 32 + q * 8));
        float4 f1 = *((const float4*)(xr + kt * 32 + q * 8 + 4));
        a[kt][0] = (short)f2bf(f0.x); a[kt][1] = (short)f2bf(f0.y);
        a[kt][2] = (short)f2bf(f0.z); a[kt][3] = (short)f2bf(f0.w);
        a[kt][4] = (short)f2bf(f1.x); a[kt][5] = (short)f2bf(f1.y);
        a[kt][6] = (short)f2bf(f1.z); a[kt][7] = (short)f2bf(f1.w);
    }
    float bc[4];
#pragma unroll
    for (int nt = 0; nt < 4; nt++) bc[nt] = bias[nt * 16 + ml];
    floatx4 acc[4];
#pragma unroll
    for (int nt = 0; nt < 4; nt++) acc[nt] = floatx4{0.f, 0.f, 0.f, 0.f};
#pragma unroll
    for (int kt = 0; kt < 4; kt++) {
#pragma unroll
        for (int nt = 0; nt < 4; nt++) {
            short8 bf = *((const short8*)(nWs + (size_t)((kt * 4 + q) * 64 + nt * 16 + ml) * 8));
            acc[nt] = __builtin_amdgcn_mfma_f32_16x16x32_bf16(a[kt], bf, acc[nt], 0, 0, 0);
        }
    }
#pragma unroll
    for (int nt = 0; nt < 4; nt++) {
#pragma unroll
        for (int r2 = 0; r2 < 4; r2++) {
            int pos = wbase + q * 4 + r2;
            if (pos < n) {
                float v = acc[nt][r2] + bc[nt];
                size_t idx = (size_t)pos * 64 + nt * 16 + ml;
                h[idx] = v;
                hn[idx] = f2bf(v);
            }
        }
    }
}

// Thread-per-(edge, 16-ch quarter): fully independent threads, no shuffles.
__global__ __launch_bounds__(256) void k_edge_enc(
    const float* __restrict__ ea, const int* __restrict__ perm,
    const float* __restrict__ W, const float* __restrict__ bias,
    u16* __restrict__ e_s, int E) {
    __shared__ float4 sW4[16 * 16];   // W[16][64] as float4 [k][c/4], 4 KB
    int t = threadIdx.x;
    if (t < 256) sW4[t] = ((const float4*)W)[t];
    __syncthreads();
    int gid = blockIdx.x * 256 + t;
    int eidx = gid >> 2, qq = gid & 3;
    if (eidx >= E) return;
    int e = perm[eidx];
    const float4* row4 = (const float4*)(ea + (size_t)e * 16);
    float4 r4[4];
    r4[0] = row4[0]; r4[1] = row4[1]; r4[2] = row4[2]; r4[3] = row4[3];
    const float* row = (const float*)r4;
    float4 acc[4];
#pragma unroll
    for (int j = 0; j < 4; j++) acc[j] = ((const float4*)bias)[qq * 4 + j];
#pragma unroll
    for (int k = 0; k < 16; k++) {
        float rv = row[k];
#pragma unroll
        for (int j = 0; j < 4; j++) {
            float4 wv = sW4[k * 16 + qq * 4 + j];
            acc[j].x += rv * wv.x; acc[j].y += rv * wv.y;
            acc[j].z += rv * wv.z; acc[j].w += rv * wv.w;
        }
    }
    u32 pk[8];
#pragma unroll
    for (int j = 0; j < 4; j++) {
        pk[2 * j]     = (u32)f2bf(acc[j].x) | ((u32)f2bf(acc[j].y) << 16);
        pk[2 * j + 1] = (u32)f2bf(acc[j].z) | ((u32)f2bf(acc[j].w) << 16);
    }
    uint4* outp = (uint4*)(e_s + (size_t)eidx * 64 + qq * 16);
    outp[0] = make_uint4(pk[0], pk[1], pk[2], pk[3]);
    outp[1] = make_uint4(pk[4], pk[5], pk[6], pk[7]);
}

// ---------------- layernorm: bf16-out (hn producer) and f32-out (final) ----------------
__global__ __launch_bounds__(256) void k_lnorm_bf(
    const float* __restrict__ h, const float* __restrict__ g, const float* __restrict__ b,
    u16* __restrict__ out, int n) {
    int t = threadIdx.x, wid = t >> 6, lane = t & 63;
    float gc = g[lane], bc = b[lane];
    for (int row = blockIdx.x * 4 + wid; row < n; row += gridDim.x * 4) {
        float v = h[(size_t)row * 64 + lane];
        float s = v;
#pragma unroll
        for (int o = 32; o > 0; o >>= 1) s += __shfl_xor(s, o);
        float mu = s * (1.f / 64.f);
        float d = v - mu;
        float s2 = d * d;
#pragma unroll
        for (int o = 32; o > 0; o >>= 1) s2 += __shfl_xor(s2, o);
        float inv = rsqrtf(s2 * (1.f / 64.f) + LN_EPS);
        float r = fmaxf(d * inv * gc + bc, 0.f);
        out[(size_t)row * 64 + lane] = f2bf(r);
    }
}

__global__ __launch_bounds__(256) void k_lnorm_out(
    const float* __restrict__ h, const float* __restrict__ g, const float* __restrict__ b,
    float* __restrict__ out, int n) {
    int t = threadIdx.x, wid = t >> 6, lane = t & 63;
    float gc = g[lane], bc = b[lane];
    for (int row = blockIdx.x * 4 + wid; row < n; row += gridDim.x * 4) {
        float v = h[(size_t)row * 64 + lane];
        float s = v;
#pragma unroll
        for (int o = 32; o > 0; o >>= 1) s += __shfl_xor(s, o);
        float mu = s * (1.f / 64.f);
        float d = v - mu;
        float s2 = d * d;
#pragma unroll
        for (int o = 32; o > 0; o >>= 1) s2 += __shfl_xor(s2, o);
        float inv = rsqrtf(s2 * (1.f / 64.f) + LN_EPS);
        out[(size_t)row * 64 + lane] = fmaxf(d * inv * gc + bc, 0.f);
    }
}

// ---------------- edge MLP (MFMA, LDS weights + 2-tile B-frag reuse — R2) ----------------
// R1: weights staged in LDS (W1 48 KB overlaid by arenas after use; W2 16 KB).
// R2: each wave owns TWO 16-edge tiles; every B-frag ds_read_b128 feeds 2 MFMAs
// (both W1 and W2 loops), halving the dominant LDS-read traffic. Bias loads
// deferred past the W1 loop to keep the live set <=128 VGPR (2 blocks/CU).
#define TILE 256
#define HSTR 136
__global__ __launch_bounds__(512, 4) void k_mlp(
    const u16* __restrict__ hn, const u16* __restrict__ e_s,
    const int* __restrict__ dsts, const int* __restrict__ srcs,
    const u16* __restrict__ W1s, const float* __restrict__ b1,
    const u16* __restrict__ W2s, const float* __restrict__ b2,
    const float* __restrict__ elng, const float* __restrict__ elnb,
    int ln_edge, u16* __restrict__ m_out, int E) {
    __shared__ __align__(16) short sW2L[8192];      // 16 KB: W2 frags (live whole kernel)
    __shared__ __align__(16) short sShared[24576];  // 48 KB: W1 frags, then per-wave arenas

    int t = threadIdx.x;
    int w = t >> 6, l = t & 63, q = l >> 4, ml = l & 15;
    int base = blockIdx.x * TILE + w * 32;
    int pos0 = base + ml;
    int pos1 = base + 16 + ml;
    bool act0 = pos0 < E, act1 = pos1 < E;
    int pp0 = act0 ? pos0 : 0, pp1 = act1 ? pos1 : 0;
    int dn0 = act0 ? dsts[pos0] : 0;
    int sn0 = act0 ? srcs[pos0] : 0;
    int dn1 = act1 ? dsts[pos1] : 0;
    int sn1 = act1 ? srcs[pos1] : 0;

    // Per-edge gathers for both tiles (issued before staging; overlaps latency).
    short8 a0[6], a1[6];
    a0[0] = *(const short8*)(hn + (size_t)dn0 * 64 + q * 8);
    a0[1] = *(const short8*)(hn + (size_t)dn0 * 64 + 32 + q * 8);
    a0[2] = *(const short8*)(hn + (size_t)sn0 * 64 + q * 8);
    a0[3] = *(const short8*)(hn + (size_t)sn0 * 64 + 32 + q * 8);
    a1[0] = *(const short8*)(hn + (size_t)dn1 * 64 + q * 8);
    a1[1] = *(const short8*)(hn + (size_t)dn1 * 64 + 32 + q * 8);
    a1[2] = *(const short8*)(hn + (size_t)sn1 * 64 + q * 8);
    a1[3] = *(const short8*)(hn + (size_t)sn1 * 64 + 32 + q * 8);
    short8 e00 = *(const short8*)(e_s + (size_t)pp0 * 64 + q * 8);
    short8 e01 = *(const short8*)(e_s + (size_t)pp0 * 64 + 32 + q * 8);
    short8 e10 = *(const short8*)(e_s + (size_t)pp1 * 64 + q * 8);
    short8 e11 = *(const short8*)(e_s + (size_t)pp1 * 64 + 32 + q * 8);

    // Stage weights global -> LDS (linear copy; frag order already pre-swizzled).
    {
        const uint4* g1 = (const uint4*)W1s;
        uint4* s1 = (uint4*)sShared;
#pragma unroll
        for (int j = 0; j < 6; j++) s1[t + j * 512] = g1[t + j * 512];
        const uint4* g2 = (const uint4*)W2s;
        uint4* s2 = (uint4*)sW2L;
#pragma unroll
        for (int j = 0; j < 2; j++) s2[t + j * 512] = g2[t + j * 512];
    }

    if (ln_edge) {
        {   // tile0 edge LN
            float ev[16];
            float sm = 0.f, sq = 0.f;
#pragma unroll
            for (int i = 0; i < 8; i++) {
                float f0 = bf2f((u16)e00[i]);
                float f1 = bf2f((u16)e01[i]);
                ev[i] = f0; ev[8 + i] = f1;
                sm += f0 + f1; sq += f0 * f0 + f1 * f1;
            }
            sm += __shfl_xor(sm, 16); sm += __shfl_xor(sm, 32);
            sq += __shfl_xor(sq, 16); sq += __shfl_xor(sq, 32);
            float mu = sm * (1.f / 64.f);
            float var = sq * (1.f / 64.f) - mu * mu;
            float inv = rsqrtf(fmaxf(var, 0.f) + LN_EPS);
#pragma unroll
            for (int i = 0; i < 8; i++) {
                int c0 = q * 8 + i, c1 = 32 + q * 8 + i;
                a0[4][i] = (short)f2bf((ev[i] - mu) * inv * elng[c0] + elnb[c0]);
                a0[5][i] = (short)f2bf((ev[8 + i] - mu) * inv * elng[c1] + elnb[c1]);
            }
        }
        {   // tile1 edge LN
            float ev[16];
            float sm = 0.f, sq = 0.f;
#pragma unroll
            for (int i = 0; i < 8; i++) {
                float f0 = bf2f((u16)e10[i]);
                float f1 = bf2f((u16)e11[i]);
                ev[i] = f0; ev[8 + i] = f1;
                sm += f0 + f1; sq += f0 * f0 + f1 * f1;
            }
            sm += __shfl_xor(sm, 16); sm += __shfl_xor(sm, 32);
            sq += __shfl_xor(sq, 16); sq += __shfl_xor(sq, 32);
            float mu = sm * (1.f / 64.f);
            float var = sq * (1.f / 64.f) - mu * mu;
            float inv = rsqrtf(fmaxf(var, 0.f) + LN_EPS);
#pragma unroll
            for (int i = 0; i < 8; i++) {
                int c0 = q * 8 + i, c1 = 32 + q * 8 + i;
                a1[4][i] = (short)f2bf((ev[i] - mu) * inv * elng[c0] + elnb[c0]);
                a1[5][i] = (short)f2bf((ev[8 + i] - mu) * inv * elng[c1] + elnb[c1]);
            }
        }
    } else {
        a0[4] = e00; a0[5] = e01;
        a1[4] = e10; a1[5] = e11;
    }

    __syncthreads();   // weights staged

    floatx4 acc0[8], acc1[8];
#pragma unroll
    for (int nt = 0; nt < 8; nt++) {
        acc0[nt] = floatx4{0.f, 0.f, 0.f, 0.f};
        acc1[nt] = floatx4{0.f, 0.f, 0.f, 0.f};
    }
#pragma unroll
    for (int kt = 0; kt < 6; kt++) {
#pragma unroll
        for (int nt = 0; nt < 8; nt++) {
            short8 bf = *((const short8*)(sShared + ((kt * 4 + q) * 128 + nt * 16 + ml) * 8));
            acc0[nt] = __builtin_amdgcn_mfma_f32_16x16x32_bf16(a0[kt], bf, acc0[nt], 0, 0, 0);
            acc1[nt] = __builtin_amdgcn_mfma_f32_16x16x32_bf16(a1[kt], bf, acc1[nt], 0, 0, 0);
        }
    }

    __syncthreads();   // all waves done reading W1 frags; arenas may overlay

    // Bias loads deferred here to keep W1-loop live set under the VGPR cap.
    float b1c[8], b2c[4];
#pragma unroll
    for (int nt = 0; nt < 8; nt++) b1c[nt] = b1[nt * 16 + ml];
#pragma unroll
    for (int nt = 0; nt < 4; nt++) b2c[nt] = b2[nt * 16 + ml];

    short* arena = sShared + w * 16 * HSTR;

    // tile0 W1-out -> arena -> A-frags
#pragma unroll
    for (int nt = 0; nt < 8; nt++) {
#pragma unroll
        for (int r2 = 0; r2 < 4; r2++) {
            float v = fmaxf(acc0[nt][r2] + b1c[nt], 0.f);
            ((u16*)arena)[(q * 4 + r2) * HSTR + nt * 16 + ml] = f2bf(v);
        }
    }
    short8 ah0[4];
#pragma unroll
    for (int kt = 0; kt < 4; kt++)
        ah0[kt] = *((const short8*)(arena + ml * HSTR + kt * 32 + q * 8));

    // tile1 W1-out -> arena -> A-frags (same region; within-wave ordering via lgkmcnt)
#pragma unroll
    for (int nt = 0; nt < 8; nt++) {
#pragma unroll
        for (int r2 = 0; r2 < 4; r2++) {
            float v = fmaxf(acc1[nt][r2] + b1c[nt], 0.f);
            ((u16*)arena)[(q * 4 + r2) * HSTR + nt * 16 + ml] = f2bf(v);
        }
    }
    short8 ah1[4];
#pragma unroll
    for (int kt = 0; kt < 4; kt++)
        ah1[kt] = *((const short8*)(arena + ml * HSTR + kt * 32 + q * 8));

    // Shared W2 loop: one B-frag read feeds both tiles.
    floatx4 c20[4], c21[4];
#pragma unroll
    for (int nt = 0; nt < 4; nt++) {
        c20[nt] = floatx4{0.f, 0.f, 0.f, 0.f};
        c21[nt] = floatx4{0.f, 0.f, 0.f, 0.f};
    }
#pragma unroll
    for (int kt = 0; kt < 4; kt++) {
#pragma unroll
        for (int nt = 0; nt < 4; nt++) {
            short8 bf = *((const short8*)(sW2L + ((kt * 4 + q) * 64 + nt * 16 + ml) * 8));
            c20[nt] = __builtin_amdgcn_mfma_f32_16x16x32_bf16(ah0[kt], bf, c20[nt], 0, 0, 0);
            c21[nt] = __builtin_amdgcn_mfma_f32_16x16x32_bf16(ah1[kt], bf, c21[nt], 0, 0, 0);
        }
    }

    // tile0 output
#pragma unroll
    for (int nt = 0; nt < 4; nt++) {
#pragma unroll
        for (int r2 = 0; r2 < 4; r2++) {
            ((u16*)arena)[(q * 4 + r2) * HSTR + nt * 16 + ml] = f2bf(c20[nt][r2] + b2c[nt]);
        }
    }
    {
        short8 m0 = *((const short8*)(arena + ml * HSTR + q * 16));
        short8 m1 = *((const short8*)(arena + ml * HSTR + q * 16 + 8));
        if (act0) {
            *((short8*)(m_out + (size_t)pos0 * 64 + q * 16)) = m0;
            *((short8*)(m_out + (size_t)pos0 * 64 + q * 16 + 8)) = m1;
        }
    }
    // tile1 output
#pragma unroll
    for (int nt = 0; nt < 4; nt++) {
#pragma unroll
        for (int r2 = 0; r2 < 4; r2++) {
            ((u16*)arena)[(q * 4 + r2) * HSTR + nt * 16 + ml] = f2bf(c21[nt][r2] + b2c[nt]);
        }
    }
    {
        short8 m0 = *((const short8*)(arena + ml * HSTR + q * 16));
        short8 m1 = *((const short8*)(arena + ml * HSTR + q * 16 + 8));
        if (act1) {
            *((short8*)(m_out + (size_t)pos1 * 64 + q * 16)) = m0;
            *((short8*)(m_out + (size_t)pos1 * 64 + q * 16 + 8)) = m1;
        }
    }
}

// ---------------- root weight: h = (add_h?h:0) + hn @ Wr  (MFMA) ----------------
__global__ __launch_bounds__(512) void k_root(
    const u16* __restrict__ hn, const u16* __restrict__ Wrs,
    float* __restrict__ h, int add_h, int n) {
    __shared__ short sA[8 * 1024];   // 16 KB
    int t = threadIdx.x;
    int base = blockIdx.x * 128;
    {
        int r = t >> 2, s = t & 3;
        int pos = base + r;
        int g = r >> 4, m = r & 15;
        short* grp = sA + g * 1024;
        bool act = pos < n;
        uint4 z4 = make_uint4(0, 0, 0, 0);
        const uint4* pd = (const uint4*)(hn + (size_t)(act ? pos : 0) * 64);
        uint4 d0 = act ? pd[2 * s] : z4;
        uint4 d1 = act ? pd[2 * s + 1] : z4;
        int ch = (s >> 1) * 4 + (s & 1) * 2;
        *((uint4*)(grp + ch * 128 + m * 8)) = d0;
        *((uint4*)(grp + (ch + 1) * 128 + m * 8)) = d1;
    }
    __syncthreads();
    int w = t >> 6, l = t & 63, q = l >> 4, ml = l & 15;
    short* arena = sA + w * 1024;
    floatx4 acc[4];
#pragma unroll
    for (int nt = 0; nt < 4; nt++) acc[nt] = floatx4{0.f, 0.f, 0.f, 0.f};
#pragma unroll
    for (int kt = 0; kt < 2; kt++) {
        short8 a = *((const short8*)(arena + (kt * 4 + q) * 128 + ml * 8));
#pragma unroll
        for (int nt = 0; nt < 4; nt++) {
            short8 bf = *((const short8*)(Wrs + (size_t)((kt * 4 + q) * 64 + nt * 16 + ml) * 8));
            acc[nt] = __builtin_amdgcn_mfma_f32_16x16x32_bf16(a, bf, acc[nt], 0, 0, 0);
        }
    }
#pragma unroll
    for (int nt = 0; nt < 4; nt++) {
#pragma unroll
        for (int r2 = 0; r2 < 4; r2++) {
            int pos = base + w * 16 + q * 4 + r2;
            if (pos < n) {
                size_t idx = (size_t)pos * 64 + nt * 16 + ml;
                float v = acc[nt][r2];
                h[idx] = add_h ? (h[idx] + v) : v;
            }
        }
    }
}

// ---------------- e += m (vectorized elementwise, bf16) ----------------
__global__ void k_eadd(u16* __restrict__ dst, const u16* __restrict__ src, long nv) {
    long i = (long)blockIdx.x * blockDim.x + threadIdx.x;
    if (i < nv) {
        uint4 a = ((const uint4*)dst)[i];
        uint4 b = ((const uint4*)src)[i];
        u32* pa = (u32*)&a;
        const u32* pb = (const u32*)&b;
        uint4 r;
        u32* pr = (u32*)&r;
#pragma unroll
        for (int k = 0; k < 4; k++) {
            float lo = bf2f((u16)(pa[k] & 0xffffu)) + bf2f((u16)(pb[k] & 0xffffu));
            float hi = bf2f((u16)(pa[k] >> 16)) + bf2f((u16)(pb[k] >> 16));
            pr[k] = (u32)f2bf(lo) | ((u32)f2bf(hi) << 16);
        }
        ((uint4*)dst)[i] = r;
    }
}

// ---------------- aggregation: online softmax over CSR, 2x unrolled ----------------
__global__ __launch_bounds__(256) void k_agg2(
    const u16* __restrict__ m_s, float* __restrict__ h,
    const int* __restrict__ offs, const float* __restrict__ tptr, int tidx,
    int n, int E) {
    int t = threadIdx.x, wid = t >> 6, lane = t & 63;
    float tv = tptr[tidx];
    for (int node = blockIdx.x * 4 + wid; node < n; node += gridDim.x * 4) {
        int p0 = clampi(offs[node], 0, E);
        int p1 = clampi(offs[node + 1], p0, E);
        float M = -1e30f, D = 0.f, S = 0.f;
        int p = p0;
        for (; p + 1 < p1; p += 2) {
            float mv0 = bf2f(m_s[(size_t)p * 64 + lane]);
            float mv1 = bf2f(m_s[(size_t)(p + 1) * 64 + lane]);
            float lg0 = mv0 * tv, lg1 = mv1 * tv;
            float Mp = fmaxf(lg0, lg1);
            float a0 = __expf(lg0 - Mp), a1 = __expf(lg1 - Mp);
            float Dp = a0 + a1, Sp = mv0 * a0 + mv1 * a1;
            float Mn = fmaxf(M, Mp);
            float xx = __expf(M - Mn), yy = __expf(Mp - Mn);
            D = D * xx + Dp * yy;
            S = S * xx + Sp * yy;
            M = Mn;
        }
        if (p < p1) {
            float mv = bf2f(m_s[(size_t)p * 64 + lane]);
            float lg = mv * tv;
            float Mn = fmaxf(M, lg);
            float xx = __expf(M - Mn), yy = __expf(lg - Mn);
            D = D * xx + yy;
            S = S * xx + mv * yy;
        }
        if (p1 > p0) h[(size_t)node * 64 + lane] += S / D;
    }
}

// ---------------- launcher ----------------
extern "C" void kernel_launch(void* const* d_in, const int* in_sizes, int n_in,
                              void* d_out, int out_size, void* d_ws, size_t ws_size,
                              hipStream_t stream) {
    float* outp = (float*)d_out;
    int FB = (out_size + 255) / 256;

    if (n_in != 17) {
        k_fill<<<FB, 256, 0, stream>>>(outp, out_size, 3.0f);
        return;
    }

    const float* x    = (const float*)d_in[0];
    const int*   ei   = (const int*)d_in[1];
    const float* ea   = (const float*)d_in[2];
    const float* nW   = (const float*)d_in[3];
    const float* nb   = (const float*)d_in[4];
    const float* eW   = (const float*)d_in[5];
    const float* eb   = (const float*)d_in[6];
    const float* cW1  = (const float*)d_in[7];
    const float* cb1  = (const float*)d_in[8];
    const float* cW2  = (const float*)d_in[9];
    const float* cb2  = (const float*)d_in[10];
    const float* cWr  = (const float*)d_in[11];
    const float* ct   = (const float*)d_in[12];
    const float* lng  = (const float*)d_in[13];
    const float* lnb  = (const float*)d_in[14];
    const float* elng = (const float*)d_in[15];
    const float* elnb = (const float*)d_in[16];

    const int n = in_sizes[0] / 128;   // 50000
    const int E = in_sizes[2] / 16;    // 500000

    char* ws = (char*)d_ws;
    size_t o = 0;
    auto alloc = [&](size_t bytes) -> void* {
        void* p = ws + o;
        o += (bytes + 255) & ~(size_t)255;
        return p;
    };
    int*   flag   = (int*)alloc(256);
    int*   deg    = (int*)alloc((size_t)n * 4);
    int*   offs   = (int*)alloc((size_t)(n + 1) * 4);
    int*   cursor = (int*)alloc((size_t)n * 4);
    int*   bsum   = (int*)alloc(256 * 4);
    int*   perm   = (int*)alloc((size_t)E * 4);
    int*   srcs   = (int*)alloc((size_t)E * 4);
    int*   dsts   = (int*)alloc((size_t)E * 4);
    float* h      = (float*)alloc((size_t)n * 64 * 4);
    u16*   hn     = (u16*)alloc((size_t)n * 64 * 2);
    u16*   bufA   = (u16*)alloc((size_t)E * 64 * 2);
    u16*   bufB   = (u16*)alloc((size_t)E * 64 * 2);
    u16*   W1s    = (u16*)alloc((size_t)3 * 24576 * 2);
    u16*   W2s    = (u16*)alloc((size_t)3 * 8192 * 2);
    u16*   Wrs    = (u16*)alloc((size_t)3 * 4096 * 2);
    u16*   nWs    = (u16*)alloc((size_t)8192 * 2);

    k_fill<<<FB, 256, 0, stream>>>(outp, out_size, 1.0f);
    if (o > ws_size) {
        k_fill<<<FB, 256, 0, stream>>>(outp, out_size, 2.0f);
        return;
    }

    int SB = (n + 255) / 256;
    k_detect<<<1, 256, 0, stream>>>(ei, E, flag);
    k_zero<<<SB, 256, 0, stream>>>(deg, n);
    k_hist<<<(E + 255) / 256, 256, 0, stream>>>(ei, flag, deg, E, n);
    k_scan1<<<SB, 256, 0, stream>>>(deg, offs, bsum, n);
    k_scan2<<<1, 256, 0, stream>>>(bsum, SB);
    k_scan3<<<SB, 256, 0, stream>>>(offs, bsum, cursor, n, E);
    k_scatter<<<(E + 255) / 256, 256, 0, stream>>>(ei, flag, cursor, perm, srcs, dsts, E, n);
    k_swz<<<(3 * 24576 + 255) / 256, 256, 0, stream>>>(cW1, cW2, cWr, nW, W1s, W2s, Wrs, nWs);
    k_node_enc<<<(n + 127) / 128, 512, 0, stream>>>(x, nWs, nb, h, hn, n);
    k_edge_enc<<<(E * 4 + 255) / 256, 256, 0, stream>>>(ea, perm, eW, eb, bufA, E);

    // Buffer schedule (ping-pong, no copies) — R8 proven:
    //  L0: mlp(in=bufA) -> bufB(m1); agg reads bufB
    //  L1: mlp(in=bufB) -> bufA(m2); agg reads bufA; eadd: bufB += bufA
    //  L2: mlp(in=bufB) -> bufA(m3); agg reads bufA
    int MB = (E + TILE - 1) / TILE;
    int RB = (n + 127) / 128;
    int AB = (n + 3) / 4;
    long nv = (long)E * 64 / 8;
    int VB = (int)((nv + 255) / 256);

    const u16* mlp_in[3]  = { bufA, bufB, bufB };
    u16*       mlp_out[3] = { bufB, bufA, bufA };

    for (int i = 0; i < 3; i++) {
        if (i > 0)
            k_lnorm_bf<<<512, 256, 0, stream>>>(h, lng + (size_t)i * 64, lnb + (size_t)i * 64, hn, n);
        k_mlp<<<MB, 512, 0, stream>>>(
            hn, mlp_in[i], dsts, srcs,
            W1s + (size_t)i * 24576, cb1 + (size_t)i * 128,
            W2s + (size_t)i * 8192, cb2 + (size_t)i * 64,
            elng + (size_t)((i > 0) ? (i - 1) : 0) * 64,
            elnb + (size_t)((i > 0) ? (i - 1) : 0) * 64,
            (i > 0) ? 1 : 0, mlp_out[i], E);
        k_root<<<RB, 512, 0, stream>>>(hn, Wrs + (size_t)i * 4096, h, (i > 0) ? 1 : 0, n);
        k_agg2<<<AB, 256, 0, stream>>>(mlp_out[i], h, offs, ct, i, n, E);
        if (i == 1)
            k_eadd<<<VB, 256, 0, stream>>>(bufB, bufA, nv);
    }
    k_lnorm_out<<<512, 256, 0, stream>>>(h, lng, lnb, outp, n);
}

// Round 3
// 527.355 us; speedup vs baseline: 1.3411x; 1.1340x over previous
//
#include <hip/hip_runtime.h>

typedef unsigned short u16;
typedef unsigned int u32;
typedef __attribute__((ext_vector_type(8))) short short8;
typedef __attribute__((ext_vector_type(4))) float floatx4;

#define LN_EPS 1e-5f

__device__ __forceinline__ float bf2f(u16 u) {
    union { u32 i; float f; } v; v.i = ((u32)u) << 16; return v.f;
}
__device__ __forceinline__ u16 f2bf(float f) {
    union { u32 i; float f; } v; v.f = f;
    u32 x = v.i;
    return (u16)((x + 0x7fffu + ((x >> 16) & 1u)) >> 16);
}
__device__ __forceinline__ int clampi(int v, int lo, int hi) {
    return v < lo ? lo : (v > hi ? hi : v);
}

// Diagnostic fill (f32).
__global__ void k_fill(float* __restrict__ out, int nel, float val) {
    int i = blockIdx.x * blockDim.x + threadIdx.x;
    if (i < nel) out[i] = val;
}

// ---------------- preprocessing ----------------
__global__ void k_zero(int* p, int n) {
    int i = blockIdx.x * blockDim.x + threadIdx.x;
    if (i < n) p[i] = 0;
}

__global__ void k_detect(const int* __restrict__ ei, int E, int* __restrict__ flag) {
    __shared__ int any;
    if (threadIdx.x == 0) any = 0;
    __syncthreads();
    int lim = (E < 4096) ? E : 4096;
    int v = 0;
    for (int i = threadIdx.x; i < lim; i += 256) v |= ei[2 * i + 1];
    if (v) atomicOr(&any, 1);
    __syncthreads();
    if (threadIdx.x == 0) flag[0] = (any == 0) ? 1 : 0;
}

__global__ void k_hist(const int* __restrict__ ei, const int* __restrict__ flag,
                       int* __restrict__ deg, int E, int n) {
    int e = blockIdx.x * blockDim.x + threadIdx.x;
    if (e < E) {
        int d = flag[0] ? ei[2 * ((size_t)E + e)] : ei[(size_t)E + e];
        atomicAdd(&deg[clampi(d, 0, n - 1)], 1);
    }
}

__global__ void k_scan1(const int* __restrict__ deg, int* __restrict__ offs,
                        int* __restrict__ bsum, int n) {
    __shared__ int s[256];
    int t = threadIdx.x;
    int i = blockIdx.x * 256 + t;
    int v = (i < n) ? deg[i] : 0;
    s[t] = v; __syncthreads();
    for (int off = 1; off < 256; off <<= 1) {
        int x = (t >= off) ? s[t - off] : 0;
        __syncthreads();
        s[t] += x;
        __syncthreads();
    }
    if (i < n) offs[i] = s[t] - v;
    if (t == 255) bsum[blockIdx.x] = s[255];
}

__global__ void k_scan2(int* bsum, int nb) {
    __shared__ int s[256];
    int t = threadIdx.x;
    int v = (t < nb) ? bsum[t] : 0;
    s[t] = v; __syncthreads();
    for (int off = 1; off < 256; off <<= 1) {
        int x = (t >= off) ? s[t - off] : 0;
        __syncthreads();
        s[t] += x;
        __syncthreads();
    }
    if (t < nb) bsum[t] = s[t] - v;
}

__global__ void k_scan3(int* __restrict__ offs, const int* __restrict__ bsum,
                        int* __restrict__ cursor, int n, int E) {
    int i = blockIdx.x * 256 + threadIdx.x;
    if (i < n) {
        int v = offs[i] + bsum[blockIdx.x];
        offs[i] = v;
        cursor[i] = v;
    }
    if (i == 0) offs[n] = E;
}

__global__ void k_scatter(const int* __restrict__ ei, const int* __restrict__ flag,
                          int* __restrict__ cursor,
                          int* __restrict__ perm, int* __restrict__ srcs,
                          int* __restrict__ dsts, int E, int n) {
    int e = blockIdx.x * blockDim.x + threadIdx.x;
    if (e < E) {
        int sv, dv;
        if (flag[0]) {
            sv = ei[2 * (size_t)e];
            dv = ei[2 * ((size_t)E + e)];
        } else {
            sv = ei[e];
            dv = ei[(size_t)E + e];
        }
        sv = clampi(sv, 0, n - 1);
        dv = clampi(dv, 0, n - 1);
        int p = clampi(atomicAdd(&cursor[dv], 1), 0, E - 1);
        perm[p] = e;
        srcs[p] = sv;
        dsts[p] = dv;
    }
}

// Pre-swizzle f32 weights into bf16 MFMA B-fragment order:
// B[k][n], k = kt*32 + q*8 + j  ->  idx = ((kt*4+q)*N + n)*8 + j
__global__ void k_swz(const float* __restrict__ W1, const float* __restrict__ W2,
                      const float* __restrict__ Wr, const float* __restrict__ nW,
                      u16* __restrict__ W1s, u16* __restrict__ W2s,
                      u16* __restrict__ Wrs, u16* __restrict__ nWs) {
    int i = blockIdx.x * blockDim.x + threadIdx.x;
    if (i < 3 * 24576) {
        int l = i / 24576, rem = i % 24576;
        int k = rem / 128, n = rem % 128;
        int kt = k >> 5, q = (k >> 3) & 3, j = k & 7;
        W1s[l * 24576 + ((kt * 4 + q) * 128 + n) * 8 + j] = f2bf(W1[i]);
    }
    if (i < 3 * 8192) {
        int l = i / 8192, rem = i % 8192;
        int k = rem / 64, n = rem % 64;
        int kt = k >> 5, q = (k >> 3) & 3, j = k & 7;
        W2s[l * 8192 + ((kt * 4 + q) * 64 + n) * 8 + j] = f2bf(W2[i]);
    }
    if (i < 3 * 4096) {
        int l = i / 4096, rem = i % 4096;
        int k = rem / 64, n = rem % 64;
        int kt = k >> 5, q = (k >> 3) & 3, j = k & 7;
        Wrs[l * 4096 + ((kt * 4 + q) * 64 + n) * 8 + j] = f2bf(Wr[i]);
    }
    if (i < 8192) {
        int k = i / 64, n = i % 64;
        int kt = k >> 5, q = (k >> 3) & 3, j = k & 7;
        nWs[((kt * 4 + q) * 64 + n) * 8 + j] = f2bf(nW[i]);
    }
}

// ---------------- node encoder (MFMA, LDS-free, barrier-free) ----------------
// 512 threads = 8 waves; wave handles 16 rows. A-frags converted f32->bf16 in regs.
__global__ __launch_bounds__(512) void k_node_enc(
    const float* __restrict__ x, const u16* __restrict__ nWs, const float* __restrict__ bias,
    float* __restrict__ h, u16* __restrict__ hn, int n) {
    int t = threadIdx.x;
    int w = t >> 6, l = t & 63, q = l >> 4, ml = l & 15;
    int wbase = blockIdx.x * 128 + w * 16;
    int rin = wbase + ml;
    int rr = (rin < n) ? rin : 0;
    const float* xr = x + (size_t)rr * 128;
    short8 a[4];
#pragma unroll
    for (int kt = 0; kt < 4; kt++) {
        float4 f0 = *((const float4*)(xr + kt * 32 + q * 8));
        float4 f1 = *((const float4*)(xr + kt * 32 + q * 8 + 4));
        a[kt][0] = (short)f2bf(f0.x); a[kt][1] = (short)f2bf(f0.y);
        a[kt][2] = (short)f2bf(f0.z); a[kt][3] = (short)f2bf(f0.w);
        a[kt][4] = (short)f2bf(f1.x); a[kt][5] = (short)f2bf(f1.y);
        a[kt][6] = (short)f2bf(f1.z); a[kt][7] = (short)f2bf(f1.w);
    }
    float bc[4];
#pragma unroll
    for (int nt = 0; nt < 4; nt++) bc[nt] = bias[nt * 16 + ml];
    floatx4 acc[4];
#pragma unroll
    for (int nt = 0; nt < 4; nt++) acc[nt] = floatx4{0.f, 0.f, 0.f, 0.f};
#pragma unroll
    for (int kt = 0; kt < 4; kt++) {
#pragma unroll
        for (int nt = 0; nt < 4; nt++) {
            short8 bf = *((const short8*)(nWs + (size_t)((kt * 4 + q) * 64 + nt * 16 + ml) * 8));
            acc[nt] = __builtin_amdgcn_mfma_f32_16x16x32_bf16(a[kt], bf, acc[nt], 0, 0, 0);
        }
    }
#pragma unroll
    for (int nt = 0; nt < 4; nt++) {
#pragma unroll
        for (int r2 = 0; r2 < 4; r2++) {
            int pos = wbase + q * 4 + r2;
            if (pos < n) {
                float v = acc[nt][r2] + bc[nt];
                size_t idx = (size_t)pos * 64 + nt * 16 + ml;
                h[idx] = v;
                hn[idx] = f2bf(v);
            }
        }
    }
}

// Thread-per-(edge, 16-ch quarter): fully independent threads, no shuffles.
__global__ __launch_bounds__(256) void k_edge_enc(
    const float* __restrict__ ea, const int* __restrict__ perm,
    const float* __restrict__ W, const float* __restrict__ bias,
    u16* __restrict__ e_s, int E) {
    __shared__ float4 sW4[16 * 16];   // W[16][64] as float4 [k][c/4], 4 KB
    int t = threadIdx.x;
    if (t < 256) sW4[t] = ((const float4*)W)[t];
    __syncthreads();
    int gid = blockIdx.x * 256 + t;
    int eidx = gid >> 2, qq = gid & 3;
    if (eidx >= E) return;
    int e = perm[eidx];
    const float4* row4 = (const float4*)(ea + (size_t)e * 16);
    float4 r4[4];
    r4[0] = row4[0]; r4[1] = row4[1]; r4[2] = row4[2]; r4[3] = row4[3];
    const float* row = (const float*)r4;
    float4 acc[4];
#pragma unroll
    for (int j = 0; j < 4; j++) acc[j] = ((const float4*)bias)[qq * 4 + j];
#pragma unroll
    for (int k = 0; k < 16; k++) {
        float rv = row[k];
#pragma unroll
        for (int j = 0; j < 4; j++) {
            float4 wv = sW4[k * 16 + qq * 4 + j];
            acc[j].x += rv * wv.x; acc[j].y += rv * wv.y;
            acc[j].z += rv * wv.z; acc[j].w += rv * wv.w;
        }
    }
    u32 pk[8];
#pragma unroll
    for (int j = 0; j < 4; j++) {
        pk[2 * j]     = (u32)f2bf(acc[j].x) | ((u32)f2bf(acc[j].y) << 16);
        pk[2 * j + 1] = (u32)f2bf(acc[j].z) | ((u32)f2bf(acc[j].w) << 16);
    }
    uint4* outp = (uint4*)(e_s + (size_t)eidx * 64 + qq * 16);
    outp[0] = make_uint4(pk[0], pk[1], pk[2], pk[3]);
    outp[1] = make_uint4(pk[4], pk[5], pk[6], pk[7]);
}

// ---------------- edge MLP (MFMA, LDS weights + 2-tile B-frag reuse — R2) ----------------
// R1: weights staged in LDS (W1 48 KB overlaid by arenas after use; W2 16 KB).
// R2: each wave owns TWO 16-edge tiles; every B-frag ds_read_b128 feeds 2 MFMAs.
// R3: optional second edge input e_s2 (residual add fused in f32 before edge-LN),
// eliminating the separate k_eadd pass over 192 MB.
#define TILE 256
#define HSTR 136
__global__ __launch_bounds__(512, 4) void k_mlp(
    const u16* __restrict__ hn, const u16* __restrict__ e_s,
    const u16* __restrict__ e_s2,
    const int* __restrict__ dsts, const int* __restrict__ srcs,
    const u16* __restrict__ W1s, const float* __restrict__ b1,
    const u16* __restrict__ W2s, const float* __restrict__ b2,
    const float* __restrict__ elng, const float* __restrict__ elnb,
    int ln_edge, u16* __restrict__ m_out, int E) {
    __shared__ __align__(16) short sW2L[8192];      // 16 KB: W2 frags (live whole kernel)
    __shared__ __align__(16) short sShared[24576];  // 48 KB: W1 frags, then per-wave arenas

    int t = threadIdx.x;
    int w = t >> 6, l = t & 63, q = l >> 4, ml = l & 15;
    int base = blockIdx.x * TILE + w * 32;
    int pos0 = base + ml;
    int pos1 = base + 16 + ml;
    bool act0 = pos0 < E, act1 = pos1 < E;
    int pp0 = act0 ? pos0 : 0, pp1 = act1 ? pos1 : 0;
    int dn0 = act0 ? dsts[pos0] : 0;
    int sn0 = act0 ? srcs[pos0] : 0;
    int dn1 = act1 ? dsts[pos1] : 0;
    int sn1 = act1 ? srcs[pos1] : 0;

    // Per-edge gathers for both tiles (issued before staging; overlaps latency).
    short8 a0[6], a1[6];
    a0[0] = *(const short8*)(hn + (size_t)dn0 * 64 + q * 8);
    a0[1] = *(const short8*)(hn + (size_t)dn0 * 64 + 32 + q * 8);
    a0[2] = *(const short8*)(hn + (size_t)sn0 * 64 + q * 8);
    a0[3] = *(const short8*)(hn + (size_t)sn0 * 64 + 32 + q * 8);
    a1[0] = *(const short8*)(hn + (size_t)dn1 * 64 + q * 8);
    a1[1] = *(const short8*)(hn + (size_t)dn1 * 64 + 32 + q * 8);
    a1[2] = *(const short8*)(hn + (size_t)sn1 * 64 + q * 8);
    a1[3] = *(const short8*)(hn + (size_t)sn1 * 64 + 32 + q * 8);
    short8 e00 = *(const short8*)(e_s + (size_t)pp0 * 64 + q * 8);
    short8 e01 = *(const short8*)(e_s + (size_t)pp0 * 64 + 32 + q * 8);
    short8 e10 = *(const short8*)(e_s + (size_t)pp1 * 64 + q * 8);
    short8 e11 = *(const short8*)(e_s + (size_t)pp1 * 64 + 32 + q * 8);
    short8 f00, f01, f10, f11;
    bool has2 = (e_s2 != nullptr);
    if (has2) {
        f00 = *(const short8*)(e_s2 + (size_t)pp0 * 64 + q * 8);
        f01 = *(const short8*)(e_s2 + (size_t)pp0 * 64 + 32 + q * 8);
        f10 = *(const short8*)(e_s2 + (size_t)pp1 * 64 + q * 8);
        f11 = *(const short8*)(e_s2 + (size_t)pp1 * 64 + 32 + q * 8);
    }

    // Stage weights global -> LDS (linear copy; frag order already pre-swizzled).
    {
        const uint4* g1 = (const uint4*)W1s;
        uint4* s1 = (uint4*)sShared;
#pragma unroll
        for (int j = 0; j < 6; j++) s1[t + j * 512] = g1[t + j * 512];
        const uint4* g2 = (const uint4*)W2s;
        uint4* s2 = (uint4*)sW2L;
#pragma unroll
        for (int j = 0; j < 2; j++) s2[t + j * 512] = g2[t + j * 512];
    }

    if (ln_edge) {
        {   // tile0 edge LN (with optional fused residual add, f32)
            float ev[16];
            float sm = 0.f, sq = 0.f;
#pragma unroll
            for (int i = 0; i < 8; i++) {
                float f0 = bf2f((u16)e00[i]);
                float f1 = bf2f((u16)e01[i]);
                if (has2) { f0 += bf2f((u16)f00[i]); f1 += bf2f((u16)f01[i]); }
                ev[i] = f0; ev[8 + i] = f1;
                sm += f0 + f1; sq += f0 * f0 + f1 * f1;
            }
            sm += __shfl_xor(sm, 16); sm += __shfl_xor(sm, 32);
            sq += __shfl_xor(sq, 16); sq += __shfl_xor(sq, 32);
            float mu = sm * (1.f / 64.f);
            float var = sq * (1.f / 64.f) - mu * mu;
            float inv = rsqrtf(fmaxf(var, 0.f) + LN_EPS);
#pragma unroll
            for (int i = 0; i < 8; i++) {
                int c0 = q * 8 + i, c1 = 32 + q * 8 + i;
                a0[4][i] = (short)f2bf((ev[i] - mu) * inv * elng[c0] + elnb[c0]);
                a0[5][i] = (short)f2bf((ev[8 + i] - mu) * inv * elng[c1] + elnb[c1]);
            }
        }
        {   // tile1 edge LN
            float ev[16];
            float sm = 0.f, sq = 0.f;
#pragma unroll
            for (int i = 0; i < 8; i++) {
                float f0 = bf2f((u16)e10[i]);
                float f1 = bf2f((u16)e11[i]);
                if (has2) { f0 += bf2f((u16)f10[i]); f1 += bf2f((u16)f11[i]); }
                ev[i] = f0; ev[8 + i] = f1;
                sm += f0 + f1; sq += f0 * f0 + f1 * f1;
            }
            sm += __shfl_xor(sm, 16); sm += __shfl_xor(sm, 32);
            sq += __shfl_xor(sq, 16); sq += __shfl_xor(sq, 32);
            float mu = sm * (1.f / 64.f);
            float var = sq * (1.f / 64.f) - mu * mu;
            float inv = rsqrtf(fmaxf(var, 0.f) + LN_EPS);
#pragma unroll
            for (int i = 0; i < 8; i++) {
                int c0 = q * 8 + i, c1 = 32 + q * 8 + i;
                a1[4][i] = (short)f2bf((ev[i] - mu) * inv * elng[c0] + elnb[c0]);
                a1[5][i] = (short)f2bf((ev[8 + i] - mu) * inv * elng[c1] + elnb[c1]);
            }
        }
    } else {
        a0[4] = e00; a0[5] = e01;
        a1[4] = e10; a1[5] = e11;
    }

    __syncthreads();   // weights staged

    floatx4 acc0[8], acc1[8];
#pragma unroll
    for (int nt = 0; nt < 8; nt++) {
        acc0[nt] = floatx4{0.f, 0.f, 0.f, 0.f};
        acc1[nt] = floatx4{0.f, 0.f, 0.f, 0.f};
    }
#pragma unroll
    for (int kt = 0; kt < 6; kt++) {
#pragma unroll
        for (int nt = 0; nt < 8; nt++) {
            short8 bf = *((const short8*)(sShared + ((kt * 4 + q) * 128 + nt * 16 + ml) * 8));
            acc0[nt] = __builtin_amdgcn_mfma_f32_16x16x32_bf16(a0[kt], bf, acc0[nt], 0, 0, 0);
            acc1[nt] = __builtin_amdgcn_mfma_f32_16x16x32_bf16(a1[kt], bf, acc1[nt], 0, 0, 0);
        }
    }

    __syncthreads();   // all waves done reading W1 frags; arenas may overlay

    // Bias loads deferred here to keep W1-loop live set under the VGPR cap.
    float b1c[8], b2c[4];
#pragma unroll
    for (int nt = 0; nt < 8; nt++) b1c[nt] = b1[nt * 16 + ml];
#pragma unroll
    for (int nt = 0; nt < 4; nt++) b2c[nt] = b2[nt * 16 + ml];

    short* arena = sShared + w * 16 * HSTR;

    // tile0 W1-out -> arena -> A-frags
#pragma unroll
    for (int nt = 0; nt < 8; nt++) {
#pragma unroll
        for (int r2 = 0; r2 < 4; r2++) {
            float v = fmaxf(acc0[nt][r2] + b1c[nt], 0.f);
            ((u16*)arena)[(q * 4 + r2) * HSTR + nt * 16 + ml] = f2bf(v);
        }
    }
    short8 ah0[4];
#pragma unroll
    for (int kt = 0; kt < 4; kt++)
        ah0[kt] = *((const short8*)(arena + ml * HSTR + kt * 32 + q * 8));

    // tile1 W1-out -> arena -> A-frags (same region; within-wave ordering via lgkmcnt)
#pragma unroll
    for (int nt = 0; nt < 8; nt++) {
#pragma unroll
        for (int r2 = 0; r2 < 4; r2++) {
            float v = fmaxf(acc1[nt][r2] + b1c[nt], 0.f);
            ((u16*)arena)[(q * 4 + r2) * HSTR + nt * 16 + ml] = f2bf(v);
        }
    }
    short8 ah1[4];
#pragma unroll
    for (int kt = 0; kt < 4; kt++)
        ah1[kt] = *((const short8*)(arena + ml * HSTR + kt * 32 + q * 8));

    // Shared W2 loop: one B-frag read feeds both tiles.
    floatx4 c20[4], c21[4];
#pragma unroll
    for (int nt = 0; nt < 4; nt++) {
        c20[nt] = floatx4{0.f, 0.f, 0.f, 0.f};
        c21[nt] = floatx4{0.f, 0.f, 0.f, 0.f};
    }
#pragma unroll
    for (int kt = 0; kt < 4; kt++) {
#pragma unroll
        for (int nt = 0; nt < 4; nt++) {
            short8 bf = *((const short8*)(sW2L + ((kt * 4 + q) * 64 + nt * 16 + ml) * 8));
            c20[nt] = __builtin_amdgcn_mfma_f32_16x16x32_bf16(ah0[kt], bf, c20[nt], 0, 0, 0);
            c21[nt] = __builtin_amdgcn_mfma_f32_16x16x32_bf16(ah1[kt], bf, c21[nt], 0, 0, 0);
        }
    }

    // tile0 output
#pragma unroll
    for (int nt = 0; nt < 4; nt++) {
#pragma unroll
        for (int r2 = 0; r2 < 4; r2++) {
            ((u16*)arena)[(q * 4 + r2) * HSTR + nt * 16 + ml] = f2bf(c20[nt][r2] + b2c[nt]);
        }
    }
    {
        short8 m0 = *((const short8*)(arena + ml * HSTR + q * 16));
        short8 m1 = *((const short8*)(arena + ml * HSTR + q * 16 + 8));
        if (act0) {
            *((short8*)(m_out + (size_t)pos0 * 64 + q * 16)) = m0;
            *((short8*)(m_out + (size_t)pos0 * 64 + q * 16 + 8)) = m1;
        }
    }
    // tile1 output
#pragma unroll
    for (int nt = 0; nt < 4; nt++) {
#pragma unroll
        for (int r2 = 0; r2 < 4; r2++) {
            ((u16*)arena)[(q * 4 + r2) * HSTR + nt * 16 + ml] = f2bf(c21[nt][r2] + b2c[nt]);
        }
    }
    {
        short8 m0 = *((const short8*)(arena + ml * HSTR + q * 16));
        short8 m1 = *((const short8*)(arena + ml * HSTR + q * 16 + 8));
        if (act1) {
            *((short8*)(m_out + (size_t)pos1 * 64 + q * 16)) = m0;
            *((short8*)(m_out + (size_t)pos1 * 64 + q * 16 + 8)) = m1;
        }
    }
}

// ---------------- root weight: h = (add_h?h:0) + hn @ Wr  (MFMA) ----------------
__global__ __launch_bounds__(512) void k_root(
    const u16* __restrict__ hn, const u16* __restrict__ Wrs,
    float* __restrict__ h, int add_h, int n) {
    __shared__ short sA[8 * 1024];   // 16 KB
    int t = threadIdx.x;
    int base = blockIdx.x * 128;
    {
        int r = t >> 2, s = t & 3;
        int pos = base + r;
        int g = r >> 4, m = r & 15;
        short* grp = sA + g * 1024;
        bool act = pos < n;
        uint4 z4 = make_uint4(0, 0, 0, 0);
        const uint4* pd = (const uint4*)(hn + (size_t)(act ? pos : 0) * 64);
        uint4 d0 = act ? pd[2 * s] : z4;
        uint4 d1 = act ? pd[2 * s + 1] : z4;
        int ch = (s >> 1) * 4 + (s & 1) * 2;
        *((uint4*)(grp + ch * 128 + m * 8)) = d0;
        *((uint4*)(grp + (ch + 1) * 128 + m * 8)) = d1;
    }
    __syncthreads();
    int w = t >> 6, l = t & 63, q = l >> 4, ml = l & 15;
    short* arena = sA + w * 1024;
    floatx4 acc[4];
#pragma unroll
    for (int nt = 0; nt < 4; nt++) acc[nt] = floatx4{0.f, 0.f, 0.f, 0.f};
#pragma unroll
    for (int kt = 0; kt < 2; kt++) {
        short8 a = *((const short8*)(arena + (kt * 4 + q) * 128 + ml * 8));
#pragma unroll
        for (int nt = 0; nt < 4; nt++) {
            short8 bf = *((const short8*)(Wrs + (size_t)((kt * 4 + q) * 64 + nt * 16 + ml) * 8));
            acc[nt] = __builtin_amdgcn_mfma_f32_16x16x32_bf16(a, bf, acc[nt], 0, 0, 0);
        }
    }
#pragma unroll
    for (int nt = 0; nt < 4; nt++) {
#pragma unroll
        for (int r2 = 0; r2 < 4; r2++) {
            int pos = base + w * 16 + q * 4 + r2;
            if (pos < n) {
                size_t idx = (size_t)pos * 64 + nt * 16 + ml;
                float v = acc[nt][r2];
                h[idx] = add_h ? (h[idx] + v) : v;
            }
        }
    }
}

// ---------------- aggregation + fused layernorm (R3) ----------------
// After the online-softmax aggregate, the wave holds the node's complete final
// 64-ch row (lane = channel). Do the LN here: write hn (bf16, relu(LN)) for the
// next layer, or the final f32 output (last layer) — removing the 4 standalone
// layernorm kernels and their h re-reads.
__global__ __launch_bounds__(256) void k_agg2(
    const u16* __restrict__ m_s, float* __restrict__ h,
    const int* __restrict__ offs, const float* __restrict__ tptr, int tidx,
    const float* __restrict__ g, const float* __restrict__ b,
    u16* __restrict__ hn_out, float* __restrict__ f32_out,
    int write_h, int n, int E) {
    int t = threadIdx.x, wid = t >> 6, lane = t & 63;
    float tv = tptr[tidx];
    float gc = g[lane], bc = b[lane];
    for (int node = blockIdx.x * 4 + wid; node < n; node += gridDim.x * 4) {
        int p0 = clampi(offs[node], 0, E);
        int p1 = clampi(offs[node + 1], p0, E);
        float M = -1e30f, D = 0.f, S = 0.f;
        int p = p0;
        for (; p + 1 < p1; p += 2) {
            float mv0 = bf2f(m_s[(size_t)p * 64 + lane]);
            float mv1 = bf2f(m_s[(size_t)(p + 1) * 64 + lane]);
            float lg0 = mv0 * tv, lg1 = mv1 * tv;
            float Mp = fmaxf(lg0, lg1);
            float a0 = __expf(lg0 - Mp), a1 = __expf(lg1 - Mp);
            float Dp = a0 + a1, Sp = mv0 * a0 + mv1 * a1;
            float Mn = fmaxf(M, Mp);
            float xx = __expf(M - Mn), yy = __expf(Mp - Mn);
            D = D * xx + Dp * yy;
            S = S * xx + Sp * yy;
            M = Mn;
        }
        if (p < p1) {
            float mv = bf2f(m_s[(size_t)p * 64 + lane]);
            float lg = mv * tv;
            float Mn = fmaxf(M, lg);
            float xx = __expf(M - Mn), yy = __expf(lg - Mn);
            D = D * xx + yy;
            S = S * xx + mv * yy;
        }
        float hv = h[(size_t)node * 64 + lane];
        if (p1 > p0) hv += S / D;
        if (write_h) h[(size_t)node * 64 + lane] = hv;
        // fused layernorm + relu
        float s = hv;
#pragma unroll
        for (int o = 32; o > 0; o >>= 1) s += __shfl_xor(s, o);
        float mu = s * (1.f / 64.f);
        float d = hv - mu;
        float s2 = d * d;
#pragma unroll
        for (int o = 32; o > 0; o >>= 1) s2 += __shfl_xor(s2, o);
        float inv = rsqrtf(s2 * (1.f / 64.f) + LN_EPS);
        float r = fmaxf(d * inv * gc + bc, 0.f);
        if (hn_out) hn_out[(size_t)node * 64 + lane] = f2bf(r);
        else        f32_out[(size_t)node * 64 + lane] = r;
    }
}

// ---------------- launcher ----------------
extern "C" void kernel_launch(void* const* d_in, const int* in_sizes, int n_in,
                              void* d_out, int out_size, void* d_ws, size_t ws_size,
                              hipStream_t stream) {
    float* outp = (float*)d_out;
    int FB = (out_size + 255) / 256;

    if (n_in != 17) {
        k_fill<<<FB, 256, 0, stream>>>(outp, out_size, 3.0f);
        return;
    }

    const float* x    = (const float*)d_in[0];
    const int*   ei   = (const int*)d_in[1];
    const float* ea   = (const float*)d_in[2];
    const float* nW   = (const float*)d_in[3];
    const float* nb   = (const float*)d_in[4];
    const float* eW   = (const float*)d_in[5];
    const float* eb   = (const float*)d_in[6];
    const float* cW1  = (const float*)d_in[7];
    const float* cb1  = (const float*)d_in[8];
    const float* cW2  = (const float*)d_in[9];
    const float* cb2  = (const float*)d_in[10];
    const float* cWr  = (const float*)d_in[11];
    const float* ct   = (const float*)d_in[12];
    const float* lng  = (const float*)d_in[13];
    const float* lnb  = (const float*)d_in[14];
    const float* elng = (const float*)d_in[15];
    const float* elnb = (const float*)d_in[16];

    const int n = in_sizes[0] / 128;   // 50000
    const int E = in_sizes[2] / 16;    // 500000

    char* ws = (char*)d_ws;
    size_t o = 0;
    auto alloc = [&](size_t bytes) -> void* {
        void* p = ws + o;
        o += (bytes + 255) & ~(size_t)255;
        return p;
    };
    int*   flag   = (int*)alloc(256);
    int*   deg    = (int*)alloc((size_t)n * 4);
    int*   offs   = (int*)alloc((size_t)(n + 1) * 4);
    int*   cursor = (int*)alloc((size_t)n * 4);
    int*   bsum   = (int*)alloc(256 * 4);
    int*   perm   = (int*)alloc((size_t)E * 4);
    int*   srcs   = (int*)alloc((size_t)E * 4);
    int*   dsts   = (int*)alloc((size_t)E * 4);
    float* h      = (float*)alloc((size_t)n * 64 * 4);
    u16*   hn     = (u16*)alloc((size_t)n * 64 * 2);
    u16*   bufA   = (u16*)alloc((size_t)E * 64 * 2);
    u16*   bufB   = (u16*)alloc((size_t)E * 64 * 2);
    u16*   W1s    = (u16*)alloc((size_t)3 * 24576 * 2);
    u16*   W2s    = (u16*)alloc((size_t)3 * 8192 * 2);
    u16*   Wrs    = (u16*)alloc((size_t)3 * 4096 * 2);
    u16*   nWs    = (u16*)alloc((size_t)8192 * 2);

    k_fill<<<FB, 256, 0, stream>>>(outp, out_size, 1.0f);
    if (o > ws_size) {
        k_fill<<<FB, 256, 0, stream>>>(outp, out_size, 2.0f);
        return;
    }

    int SB = (n + 255) / 256;
    k_detect<<<1, 256, 0, stream>>>(ei, E, flag);
    k_zero<<<SB, 256, 0, stream>>>(deg, n);
    k_hist<<<(E + 255) / 256, 256, 0, stream>>>(ei, flag, deg, E, n);
    k_scan1<<<SB, 256, 0, stream>>>(deg, offs, bsum, n);
    k_scan2<<<1, 256, 0, stream>>>(bsum, SB);
    k_scan3<<<SB, 256, 0, stream>>>(offs, bsum, cursor, n, E);
    k_scatter<<<(E + 255) / 256, 256, 0, stream>>>(ei, flag, cursor, perm, srcs, dsts, E, n);
    k_swz<<<(3 * 24576 + 255) / 256, 256, 0, stream>>>(cW1, cW2, cWr, nW, W1s, W2s, Wrs, nWs);
    k_node_enc<<<(n + 127) / 128, 512, 0, stream>>>(x, nWs, nb, h, hn, n);
    k_edge_enc<<<(E * 4 + 255) / 256, 256, 0, stream>>>(ea, perm, eW, eb, bufA, E);

    // Buffer schedule (ping-pong, no copies):
    //  L0: mlp(in=bufA)            -> bufB(m1); agg reads bufB, fuses LN->hn (lng[1])
    //  L1: mlp(in=bufB)            -> bufA(m2); agg reads bufA, fuses LN->hn (lng[2])
    //  L2: mlp(in=bufB, in2=bufA)  -> bufA(m3); agg reads bufA, fuses LN->out (lng[0])
    //  (L2's in2 path replaces the old k_eadd 192 MB pass.)
    int MB = (E + TILE - 1) / TILE;
    int RB = (n + 127) / 128;
    int AB = (n + 3) / 4;

    const u16* mlp_in[3]  = { bufA, bufB, bufB };
    const u16* mlp_in2[3] = { nullptr, nullptr, bufA };
    u16*       mlp_out[3] = { bufB, bufA, bufA };

    for (int i = 0; i < 3; i++) {
        k_mlp<<<MB, 512, 0, stream>>>(
            hn, mlp_in[i], mlp_in2[i], dsts, srcs,
            W1s + (size_t)i * 24576, cb1 + (size_t)i * 128,
            W2s + (size_t)i * 8192, cb2 + (size_t)i * 64,
            elng + (size_t)((i > 0) ? (i - 1) : 0) * 64,
            elnb + (size_t)((i > 0) ? (i - 1) : 0) * 64,
            (i > 0) ? 1 : 0, mlp_out[i], E);
        k_root<<<RB, 512, 0, stream>>>(hn, Wrs + (size_t)i * 4096, h, (i > 0) ? 1 : 0, n);
        if (i < 2) {
            // LN params for layer i+1's input norm
            k_agg2<<<AB, 256, 0, stream>>>(mlp_out[i], h, offs, ct, i,
                                           lng + (size_t)(i + 1) * 64, lnb + (size_t)(i + 1) * 64,
                                           hn, nullptr, 1, n, E);
        } else {
            // final output norm (layer-0 params), relu, f32 out; h store skipped
            k_agg2<<<AB, 256, 0, stream>>>(mlp_out[i], h, offs, ct, i,
                                           lng, lnb,
                                           nullptr, outp, 0, n, E);
        }
    }
}